// Round 11
// baseline (56.924 us; speedup 1.0000x reference)
//
#include <hip/hip_runtime.h>

#define TOT 288
#define W1C 6.2340979026f   // 2*pi*127/128
#define TWOPI_128 0.049087385212340517f

typedef short short8 __attribute__((ext_vector_type(8)));
typedef float f32x4 __attribute__((ext_vector_type(4)));
typedef unsigned short u16;
typedef u16 u16x8 __attribute__((ext_vector_type(8)));

__device__ __forceinline__ u16 f2bf(float f) {
    unsigned u = __builtin_bit_cast(unsigned, f);
    u += 0x7fffu + ((u >> 16) & 1u);
    return (u16)(u >> 16);
}
__device__ __forceinline__ float2 cmul(float2 a, float2 b) {
    return make_float2(a.x * b.x - a.y * b.y, a.x * b.y + a.y * b.x);
}
__device__ __forceinline__ float2 cadd(float2 a, float2 b) {
    return make_float2(a.x + b.x, a.y + b.y);
}
__device__ __forceinline__ float2 cfma(float2 a, float2 b, float2 c) {
    return make_float2(c.x + a.x * b.x - a.y * b.y, c.y + a.x * b.y + a.y * b.x);
}
__device__ __forceinline__ void chi_basis(int f, float2 c[3]) {
    if (f == 0) {
        c[0] = make_float2(1.f, 0.f); c[1] = make_float2(0.f, 0.f); c[2] = make_float2(0.f, 0.f);
    } else {
        float w = W1C * (float)f;
        float iw = 1.0f / w;
        c[0] = make_float2(0.f, 0.f);
        c[1] = make_float2(0.f, -iw);
        c[2] = make_float2(-iw * iw, 0.f);
    }
}

// ---------------- workspace layout (float offsets) ----------------
// alpha  :      256  (131072)   [b][i][f][g] float2
// Dv     :  1179904  (18432)    [o][i][jk=9] float2
// CaG    :  1198336  (9216)     [b*32+i][jk=9] float2
// or1    :  1704192  (131072)   [b][o][f][g] float2
// S      :  1966336  (262144)   [o][nm=16][pq=256] float2
// fA     :  6160640  (2048)     bf16 Fourier A table
// fB     :  6162688  (2048)     bf16 Fourier B table
// or2p   :  6164736  (1048576)  partial or2 [ic=8][bo=256][pq=256] float2

// ============ k_pre: alpha (0..255, LDS-staged Goertzel) | S (256..287) | D (288..415) | tf (416)
__global__ __launch_bounds__(256) void k_pre(const float* __restrict__ x,
                                             const float* __restrict__ wr,
                                             const float* __restrict__ wi,
                                             float2* __restrict__ alpha,
                                             float2* __restrict__ Sv,
                                             float2* __restrict__ Dv,
                                             u16* __restrict__ fA, u16* __restrict__ fB) {
    __shared__ float sm[16384];         // alpha: staged image (64 KB), reused for T1
    const int bid = blockIdx.x;
    const int t = threadIdx.x;

    if (bid < 256) {
        // ----- alpha[bi,f,g]: 16x16 DFT corner; x staged to LDS async, Goertzel both passes -----
        const int bi = bid;
        const float* xp = x + (size_t)bi * 16384;
        const int l = t & 63, w4 = t >> 6;

        // stage 64 KB: wave w4 stages rows y in [w4*32, w4*32+32); 16 rounds x 1 KB
#pragma unroll
        for (int r = 0; r < 16; ++r) {
            int off = w4 * 4096 + r * 256;             // floats (wave-uniform)
            __builtin_amdgcn_global_load_lds(
                (const __attribute__((address_space(1))) unsigned*)(xp + off + l * 4),
                (__attribute__((address_space(3))) unsigned*)(sm + off), 16, 0, 0);
        }

        // overlap: twiddle init while loads fly
        const int xc = t & 127;
        const int ft = (t >> 7) * 8;
        float c2[8], ccs[8], csn[8], s1[8], s2[8];
#pragma unroll
        for (int j = 0; j < 8; ++j) {
            float w = TWOPI_128 * (float)(ft + j);
            sincosf(w, &csn[j], &ccs[j]);
            c2[j] = 2.f * ccs[j];
            s1[j] = 0.f; s2[j] = 0.f;
        }
        __syncthreads();   // drains global_load_lds (vmcnt 0 before barrier)

        // phase 1: column Goertzel from LDS (conflict-free: consecutive xc per lane)
#pragma unroll 4
        for (int y = 0; y < 128; ++y) {
            float xv = sm[y * 128 + xc];
#pragma unroll
            for (int j = 0; j < 8; ++j) {
                float na = __builtin_fmaf(c2[j], s1[j], xv - s2[j]);
                s2[j] = s1[j]; s1[j] = na;
            }
        }
        float t1r[8], t1i[8];
#pragma unroll
        for (int j = 0; j < 8; ++j) {
            t1r[j] = ccs[j] * s1[j] - s2[j];
            t1i[j] = csn[j] * s1[j];
        }
        __syncthreads();   // all x reads done; safe to overwrite sm with T1

        float2* T1c = (float2*)sm;     // [16][132] padded, 4224 floats
#pragma unroll
        for (int j = 0; j < 8; ++j)
            T1c[(ft + j) * 132 + xc] = make_float2(t1r[j], t1i[j]);
        __syncthreads();

        // phase 2: row Goertzel over complex T1
        const int f = t >> 4, g = t & 15;
        const float2* tp = T1c + f * 132;
        float sw, cw;
        sincosf(TWOPI_128 * (float)g, &sw, &cw);
        float c2g = 2.f * cw;
        float s1r = 0.f, s1i = 0.f, s2r = 0.f, s2i = 0.f;
#pragma unroll 4
        for (int xx = 0; xx < 128; ++xx) {
            float2 v = tp[xx];
            float nr = __builtin_fmaf(c2g, s1r, v.x - s2r);
            s2r = s1r; s1r = nr;
            float ni = __builtin_fmaf(c2g, s1i, v.y - s2i);
            s2i = s1i; s1i = ni;
        }
        alpha[bi * 256 + t] = make_float2(cw * s1r - sw * s1i - s2r,
                                          sw * s1r + cw * s1i - s2i);
    } else if (bid < 288) {
        // ----- S_o[n,m,p,q] Taylor moments for x2 polynomial -----
        int o = bid - 256;
        int p = t >> 4, q = t & 15;
        float Sr[4][4], Si[4][4];
#pragma unroll
        for (int n = 0; n < 4; ++n)
#pragma unroll
            for (int m = 0; m < 4; ++m) { Sr[n][m] = 0.f; Si[n][m] = 0.f; }
        for (int i = 0; i < 32; ++i) {
            int io = i * 32 + o;
            float p1r = wr[io * TOT + p],      p1i = wi[io * TOT + p];
            float p2r = wr[io * TOT + 16 + q], p2i = wi[io * TOT + 16 + q];
            float a1r[4], a1i[4], a2r[4], a2i[4];
            a1r[0] = 1.f; a1i[0] = 0.f;
            a2r[0] = 1.f; a2i[0] = 0.f;
#pragma unroll
            for (int n = 1; n < 4; ++n) {
                a1r[n] = a1r[n-1] * p1r - a1i[n-1] * p1i;
                a1i[n] = a1r[n-1] * p1i + a1i[n-1] * p1r;
                a2r[n] = a2r[n-1] * p2r - a2i[n-1] * p2i;
                a2i[n] = a2r[n-1] * p2i + a2i[n-1] * p2r;
            }
#pragma unroll
            for (int n = 0; n < 4; ++n)
#pragma unroll
                for (int m = 0; m < 4; ++m) {
                    Sr[n][m] += a1r[n] * a2r[m] - a1i[n] * a2i[m];
                    Si[n][m] += a1r[n] * a2i[m] + a1i[n] * a2r[m];
                }
        }
        const float facs[4] = {1.f, 1.f, 0.5f, 0.16666666666f};
        const float isz = 1.0f / 16384.0f;
#pragma unroll
        for (int n = 0; n < 4; ++n)
#pragma unroll
            for (int m = 0; m < 4; ++m) {
                float fac = facs[n] * facs[m] * isz;
                Sv[(size_t)(o * 16 + n * 4 + m) * 256 + t] =
                    make_float2(Sr[n][m] * fac, Si[n][m] * fac);
            }
    } else if (bid < 416) {
        // ----- D_jk[i,o] = sum_pq phi_j[p] * R[p,q] * psi_k[q] -----
        int base = (bid - 288) * 8;
        int wp = t >> 6, l = t & 63;
#pragma unroll
        for (int s = 0; s < 2; ++s) {
            int io = base + wp * 2 + s;
            float2 Dacc[9];
#pragma unroll
            for (int jk = 0; jk < 9; ++jk) Dacc[jk] = make_float2(0.f, 0.f);
#pragma unroll
            for (int k = 0; k < 4; ++k) {
                int e = l + 64 * k;
                int p = e >> 4, q = e & 15;
                float2 p1 = make_float2(wr[io * TOT + p], wi[io * TOT + p]);
                float i1 = 1.0f / (p1.x * p1.x + p1.y * p1.y);
                float2 phip = make_float2(-p1.x * i1, p1.y * i1);
                float2 p2 = make_float2(wr[io * TOT + 16 + q], wi[io * TOT + 16 + q]);
                float i2 = 1.0f / (p2.x * p2.x + p2.y * p2.y);
                float2 psip = make_float2(-p2.x * i2, p2.y * i2);
                float2 R = make_float2(wr[io * TOT + 32 + e], wi[io * TOT + 32 + e]);
                float2 Rphi[3] = {cmul(R, phip), R, cmul(R, p1)};
                float2 psi[3] = {psip, make_float2(1.f, 0.f), p2};
#pragma unroll
                for (int j = 0; j < 3; ++j)
#pragma unroll
                    for (int k2 = 0; k2 < 3; ++k2)
                        Dacc[j * 3 + k2] = cfma(Rphi[j], psi[k2], Dacc[j * 3 + k2]);
            }
#pragma unroll
            for (int jk = 0; jk < 9; ++jk) {
#pragma unroll
                for (int m = 32; m >= 1; m >>= 1) {
                    Dacc[jk].x += __shfl_xor(Dacc[jk].x, m);
                    Dacc[jk].y += __shfl_xor(Dacc[jk].y, m);
                }
            }
            if (l == 0) {
                int o = io & 31, i = io >> 5;
#pragma unroll
                for (int jk = 0; jk < 9; ++jk)
                    Dv[(size_t)(o * 32 + i) * 9 + jk] = Dacc[jk];
            }
        }
    } else {
        // ----- tf: Fourier bf16 tables -----
        for (int cidx = t; cidx < 1024; cidx += 256) {
            int tbl = cidx >> 9, mc = cidx & 511;
            int z = mc >> 2, cp = mc & 3;
            int c = cp ^ ((z >> 1) & 3);
            u16x8 v;
#pragma unroll
            for (int j = 0; j < 8; ++j) {
                int k = c * 8 + j, f = k & 15, part = k >> 4;
                float th = TWOPI_128 * (float)((f * z) & 127);
                float s, cs;
                sincosf(th, &s, &cs);
                float val = part ? ((tbl == 0) ? s : -s) : cs;
                v[j] = f2bf(val);
            }
            u16* dst = (tbl == 0 ? fA : fB) + mc * 8;
            *(u16x8*)dst = v;
        }
    }
}

// ============ k_ca: or1 (0..255) | Ca moments (256..511, one per (b,i))
__global__ __launch_bounds__(256) void k_ca(const float2* __restrict__ alpha,
                                            const float2* __restrict__ Dv,
                                            float2* __restrict__ or1,
                                            float2* __restrict__ CaG) {
    __shared__ float2 red[4][9];
    const int bid = blockIdx.x;
    const int t = threadIdx.x;

    if (bid < 256) {
        // ----- or1[b,o,f,g] = sum_i alpha[b,i,f,g] * s1_i(f,g) -----
        int bo = bid;
        int b = bo >> 5, o = bo & 31;
        int f = t >> 4, g = t & 15;
        float2 X[3], Xi[3];
        chi_basis(f, X);
        chi_basis(g, Xi);
        float2 B[9];
#pragma unroll
        for (int j = 0; j < 3; ++j)
#pragma unroll
            for (int k = 0; k < 3; ++k)
                B[j * 3 + k] = cmul(X[j], Xi[k]);
        float2 acc = make_float2(0.f, 0.f);
        for (int i = 0; i < 32; ++i) {
            const float2* Dp = Dv + (size_t)(o * 32 + i) * 9;
            float2 s1v = make_float2(0.f, 0.f);
#pragma unroll
            for (int jk = 0; jk < 9; ++jk)
                s1v = cfma(Dp[jk], B[jk], s1v);
            float2 a = alpha[(b * 32 + i) * 256 + t];
            acc = cfma(a, s1v, acc);
        }
        or1[bo * 256 + t] = acc;
    } else {
        // ----- Ca_jk[b,i] = sum_fg chi_j[f] * alpha[b,i,f,g] * xi_k[g] -----
        int idx = bid - 256;           // b*32 + i
        int f = t >> 4, g = t & 15;
        float2 X[3], Xi[3];
        chi_basis(f, X);
        chi_basis(g, Xi);
        float2 a = alpha[(size_t)idx * 256 + t];
        float2 aX0 = cmul(a, X[0]), aX1 = cmul(a, X[1]), aX2 = cmul(a, X[2]);
        float2 Ca[9];
        Ca[0] = cmul(aX0, Xi[0]); Ca[1] = cmul(aX0, Xi[1]); Ca[2] = cmul(aX0, Xi[2]);
        Ca[3] = cmul(aX1, Xi[0]); Ca[4] = cmul(aX1, Xi[1]); Ca[5] = cmul(aX1, Xi[2]);
        Ca[6] = cmul(aX2, Xi[0]); Ca[7] = cmul(aX2, Xi[1]); Ca[8] = cmul(aX2, Xi[2]);
#pragma unroll
        for (int jk = 0; jk < 9; ++jk) {
#pragma unroll
            for (int m = 32; m >= 1; m >>= 1) {
                Ca[jk].x += __shfl_xor(Ca[jk].x, m);
                Ca[jk].y += __shfl_xor(Ca[jk].y, m);
            }
        }
        int l = t & 63, w = t >> 6;
        if (l == 0) {
#pragma unroll
            for (int jk = 0; jk < 9; ++jk) red[w][jk] = Ca[jk];
        }
        __syncthreads();
        if (t < 9) {
            float2 s = cadd(cadd(red[0][t], red[1][t]), cadd(red[2][t], red[3][t]));
            CaG[(size_t)idx * 9 + t] = s;
        }
    }
}

// ============ k_or2: partial or2 via 3x3 bilinear form (reads precomputed Ca)
__global__ __launch_bounds__(256) void k_or2(const float* __restrict__ wr,
                                             const float* __restrict__ wi,
                                             const float2* __restrict__ CaG,
                                             float2* __restrict__ or2p) {
    __shared__ float2 CaL[36];
    const int bid = blockIdx.x;
    const int bo = bid & 255;
    const int ic = bid >> 8;
    const int b = bo >> 5, o = bo & 31;
    const int t = threadIdx.x;

    if (t < 36) CaL[t] = CaG[(size_t)(b * 32 + ic * 4) * 9 + t];
    __syncthreads();

    const int p_ = t >> 4, q_ = t & 15;
    float2 acc = make_float2(0.f, 0.f);
#pragma unroll
    for (int ii = 0; ii < 4; ++ii) {
        int i = ic * 4 + ii;
        int io = i * 32 + o;
        float2 p1 = make_float2(wr[io * TOT + p_], wi[io * TOT + p_]);
        float i1 = 1.0f / (p1.x * p1.x + p1.y * p1.y);
        float2 phip = make_float2(-p1.x * i1, p1.y * i1);
        float2 p2 = make_float2(wr[io * TOT + 16 + q_], wi[io * TOT + 16 + q_]);
        float i2 = 1.0f / (p2.x * p2.x + p2.y * p2.y);
        float2 psip = make_float2(-p2.x * i2, p2.y * i2);
        float2 R = make_float2(wr[io * TOT + 32 + t], wi[io * TOT + 32 + t]);
        float2 c0 = CaL[ii * 9 + 0], c1 = CaL[ii * 9 + 1], c2 = CaL[ii * 9 + 2];
        float2 c3 = CaL[ii * 9 + 3], c4 = CaL[ii * 9 + 4], c5 = CaL[ii * 9 + 5];
        float2 c6 = CaL[ii * 9 + 6], c7 = CaL[ii * 9 + 7], c8 = CaL[ii * 9 + 8];
        float2 col0 = cfma(c6, p1, cfma(c0, phip, c3));
        float2 col1 = cfma(c7, p1, cfma(c1, phip, c4));
        float2 col2 = cfma(c8, p1, cfma(c2, phip, c5));
        float2 T = cfma(col2, p2, cfma(col0, psip, col1));
        acc = cfma(R, T, acc);
    }
    or2p[(size_t)ic * 65536 + bo * 256 + t] = acc;
}

// ============ k_x12m: single Fourier MFMA term + 4x4 Taylor polynomial for x2.
__global__ __launch_bounds__(512, 4) void k_x12m(
        const float2* __restrict__ or1v,
        const float2* __restrict__ or2p,
        const float2* __restrict__ Sv,
        const u16* __restrict__ fA,
        const u16* __restrict__ fB,
        float* __restrict__ out) {
    __shared__ u16 EA[2048];
    __shared__ u16 EB[4096];
    __shared__ u16 GL[2048];
    __shared__ float2 SM1[256];
    __shared__ float2 SM2[256];
    __shared__ float CP[16];

    const int t = threadIdx.x;
    const int l = t & 63, w = t >> 6;
    const int bid = blockIdx.x;
    const int o = bid & 31, b = (bid >> 5) & 7, zh = bid >> 8;
    const int bo = b * 32 + o;
    const int q = l & 15, c4 = l >> 4, k0 = c4 * 8;

    for (int ch = w; ch < 12; ch += 8) {
        const u16* g;
        u16* d;
        if (ch < 4) { g = fA + zh * 2048 + ch * 512 + l * 8; d = &EA[ch * 512]; }
        else { g = fB + (ch - 4) * 512 + l * 8; d = &EB[(ch - 4) * 512]; }
        __builtin_amdgcn_global_load_lds(
            (const __attribute__((address_space(1))) unsigned*)g,
            (__attribute__((address_space(3))) unsigned*)d, 16, 0, 0);
    }

    if (t < 256) {
        float sr = 0.f, si = 0.f;
#pragma unroll
        for (int ic = 0; ic < 8; ++ic) {
            float2 v = or2p[(size_t)ic * 65536 + bo * 256 + t];
            sr += v.x; si += v.y;
        }
        SM2[t] = make_float2(sr, si);
        SM1[t] = or1v[bo * 256 + t];
    }
    __syncthreads();

    {
        int gidx = t >> 5;
        int j = t & 31;
        const float2* Sg = Sv + (size_t)(o * 16 + gidx) * 256;
        float part = 0.f;
#pragma unroll
        for (int k = 0; k < 8; ++k) {
            int pq = j + 32 * k;
            float2 s = Sg[pq];
            float2 v = SM2[pq];
            part += v.x * s.x - v.y * s.y;
        }
#pragma unroll
        for (int msk = 16; msk >= 1; msk >>= 1)
            part += __shfl_xor(part, msk, 32);
        if (j == 0) CP[gidx] = part;
    }

    short8 mF0, mF1;
#pragma unroll
    for (int j = 0; j < 8; ++j) {
        int k = k0 + j, f = k & 15;
        float2 m1 = SM1[f * 16 + q];
        if (k < 16) { mF0[j] = (short)f2bf(m1.x); mF1[j] = (short)f2bf(m1.y); }
        else        { mF0[j] = (short)f2bf(-m1.y); mF1[j] = (short)f2bf(m1.x); }
    }
    const short8 bF = (w & 1) ? mF1 : mF0;

    const int zt_g = w >> 1;
    const int zL_g = zt_g * 16 + q;
    const int cw_g = c4 ^ ((zL_g >> 1) & 3);
    const int kk_g = q + ((w & 1) << 4);
    const int x_ = w * 16 + q;
    const int cb_ = c4 ^ ((x_ >> 1) & 3);

    {
        short8 aG = *(const short8*)&EA[zL_g * 32 + cw_g * 8];
        f32x4 g = (f32x4){0.f, 0.f, 0.f, 0.f};
        g = __builtin_amdgcn_mfma_f32_16x16x32_bf16(aG, bF, g, 0, 0, 0);
#pragma unroll
        for (int r = 0; r < 4; ++r) {
            int zz = zt_g * 16 + c4 * 4 + r;
            int cc = (kk_g >> 3) ^ ((zz >> 1) & 3);
            GL[zz * 32 + cc * 8 + (kk_g & 7)] = f2bf(g[r]);
        }
    }
    __syncthreads();

    f32x4 acc[4];
    {
        short8 bf = *(const short8*)&EB[x_ * 32 + cb_ * 8];
#pragma unroll
        for (int zt = 0; zt < 4; ++zt) {
            int zL = zt * 16 + q;
            int ca = c4 ^ ((zL >> 1) & 3);
            short8 af = *(const short8*)&GL[zL * 32 + ca * 8];
            f32x4 a = (f32x4){0.f, 0.f, 0.f, 0.f};
            acc[zt] = __builtin_amdgcn_mfma_f32_16x16x32_bf16(af, bf, a, 0, 0, 0);
        }
    }

    const float sc = 1.0f / 16384.0f;
    const float tx = (float)x_ * 0.007874015748031496f;
    float R[4];
#pragma unroll
    for (int n = 0; n < 4; ++n)
        R[n] = ((CP[n * 4 + 3] * tx + CP[n * 4 + 2]) * tx + CP[n * 4 + 1]) * tx + CP[n * 4 + 0];
#pragma unroll
    for (int zt = 0; zt < 4; ++zt) {
        int zbase = zh * 64 + zt * 16 + c4 * 4;
        f32x4 a = acc[zt];
#pragma unroll
        for (int r = 0; r < 4; ++r) {
            float tz = (float)(zbase + r) * 0.007874015748031496f;
            float poly = ((R[3] * tz + R[2]) * tz + R[1]) * tz + R[0];
            out[(size_t)bo * 16384 + (zbase + r) * 128 + x_] = a[r] * sc + poly;
        }
    }
}

extern "C" void kernel_launch(void* const* d_in, const int* in_sizes, int n_in,
                              void* d_out, int out_size, void* d_ws, size_t ws_size,
                              hipStream_t stream) {
    const float* x  = (const float*)d_in[0];
    const float* wr = (const float*)d_in[1];
    const float* wi = (const float*)d_in[2];
    float* out = (float*)d_out;
    float* ws = (float*)d_ws;

    float2* alpha = (float2*)(ws + 256);
    float2* Dv    = (float2*)(ws + 1179904);
    float2* CaG   = (float2*)(ws + 1198336);
    float2* or1   = (float2*)(ws + 1704192);
    float2* Sv    = (float2*)(ws + 1966336);
    u16*    fA    = (u16*)(ws + 6160640);
    u16*    fB    = (u16*)(ws + 6162688);
    float2* or2p  = (float2*)(ws + 6164736);

    hipLaunchKernelGGL(k_pre,  dim3(417),  dim3(256), 0, stream,
                       x, wr, wi, alpha, Sv, Dv, fA, fB);
    hipLaunchKernelGGL(k_ca,   dim3(512),  dim3(256), 0, stream,
                       alpha, Dv, or1, CaG);
    hipLaunchKernelGGL(k_or2,  dim3(2048), dim3(256), 0, stream,
                       wr, wi, CaG, or2p);
    hipLaunchKernelGGL(k_x12m, dim3(512),  dim3(512), 0, stream,
                       or1, or2p, Sv, fA, fB, out);
}

// Round 12
// 51.030 us; speedup vs baseline: 1.1155x; 1.1155x over previous
//
#include <hip/hip_runtime.h>

#define TOT 288
#define W1C 6.2340979026f   // 2*pi*127/128

typedef short short8 __attribute__((ext_vector_type(8)));
typedef float f32x4 __attribute__((ext_vector_type(4)));
typedef unsigned short u16;
typedef u16 u16x8 __attribute__((ext_vector_type(8)));

__device__ __forceinline__ u16 f2bf(float f) {
    unsigned u = __builtin_bit_cast(unsigned, f);
    u += 0x7fffu + ((u >> 16) & 1u);
    return (u16)(u >> 16);
}
__device__ __forceinline__ float2 cmul(float2 a, float2 b) {
    return make_float2(a.x * b.x - a.y * b.y, a.x * b.y + a.y * b.x);
}
__device__ __forceinline__ float2 cfma(float2 a, float2 b, float2 c) {
    return make_float2(c.x + a.x * b.x - a.y * b.y, c.y + a.x * b.y + a.y * b.x);
}
__device__ __forceinline__ void chi_basis(int f, float2 c[3]) {
    if (f == 0) {
        c[0] = make_float2(1.f, 0.f); c[1] = make_float2(0.f, 0.f); c[2] = make_float2(0.f, 0.f);
    } else {
        float w = W1C * (float)f;
        float iw = 1.0f / w;
        c[0] = make_float2(0.f, 0.f);
        c[1] = make_float2(0.f, -iw);
        c[2] = make_float2(-iw * iw, 0.f);
    }
}

// ---------------- workspace layout (float offsets) ----------------
// alpha  :      256  (131072)   [b][i][f][g] float2
// Dv     :  1179904  (18432)    [o][i][jk=9] float2
// or1    :  1704192  (131072)   [b][o][f][g] float2
// S      :  1966336  (262144)   [o][nm=16][pq=256] float2
// fA     :  6160640  (2048)     bf16 Fourier A table
// fB     :  6162688  (2048)     bf16 Fourier B table
// or2p   :  6164736  (1048576)  partial or2 [ic=8][bo=256][pq=256] float2

// ============ k_pre: alpha (0..255) | S (256..287) | D (288..415) | tf (416)
__global__ __launch_bounds__(256) void k_pre(const float* __restrict__ x,
                                             const float* __restrict__ wr,
                                             const float* __restrict__ wi,
                                             float2* __restrict__ Sv,
                                             float2* __restrict__ Dv,
                                             u16* __restrict__ fA, u16* __restrict__ fB,
                                             float2* __restrict__ alpha) {
    __shared__ float sm[4352];
    const int bid = blockIdx.x;
    const int t = threadIdx.x;

    if (bid < 256) {
        // ----- alpha: partial 2D DFT corner, register-rotation twiddles -----
        float* T1r = sm;            // 16 x 132 (padded stride)
        float* T1i = sm + 2112;
        int bi = bid;
        const float* xp = x + (size_t)bi * 16384;
        int xcol = t & 127;
        int f0 = (t >> 7) * 8;
        float ar[8], ai[8], rcr[8], rci[8], str[8], sti[8];
#pragma unroll
        for (int j = 0; j < 8; ++j) {
            ar[j] = 0.f; ai[j] = 0.f;
            rcr[j] = 1.f; rci[j] = 0.f;
            float s, c;
            sincosf(0.049087385212340517f * (float)(f0 + j), &s, &c);
            str[j] = c; sti[j] = -s;
        }
        for (int y = 0; y < 128; ++y) {
            float xv = xp[y * 128 + xcol];
#pragma unroll
            for (int j = 0; j < 8; ++j) {
                ar[j] += rcr[j] * xv;
                ai[j] += rci[j] * xv;
                float nr = rcr[j] * str[j] - rci[j] * sti[j];
                rci[j] = rcr[j] * sti[j] + rci[j] * str[j];
                rcr[j] = nr;
            }
        }
#pragma unroll
        for (int j = 0; j < 8; ++j) {
            T1r[(f0 + j) * 132 + xcol] = ar[j];
            T1i[(f0 + j) * 132 + xcol] = ai[j];
        }
        __syncthreads();

        int g = t & 15, f = t >> 4;
        float sr = 0.f, si = 0.f;
        float c2r = 1.f, c2i = 0.f, s2r, s2i;
        {
            float s, c;
            sincosf(0.049087385212340517f * (float)g, &s, &c);
            s2r = c; s2i = -s;
        }
        for (int xx = 0; xx < 128; ++xx) {
            float trv = T1r[f * 132 + xx], tiv = T1i[f * 132 + xx];
            sr += trv * c2r - tiv * c2i;
            si += trv * c2i + tiv * c2r;
            float nr = c2r * s2r - c2i * s2i;
            c2i = c2r * s2i + c2i * s2r;
            c2r = nr;
        }
        alpha[bi * 256 + t] = make_float2(sr, si);
    } else if (bid < 288) {
        // ----- S_o[n,m,p,q] Taylor moments for x2 polynomial -----
        int o = bid - 256;
        int p = t >> 4, q = t & 15;
        float Sr[4][4], Si[4][4];
#pragma unroll
        for (int n = 0; n < 4; ++n)
#pragma unroll
            for (int m = 0; m < 4; ++m) { Sr[n][m] = 0.f; Si[n][m] = 0.f; }
        for (int i = 0; i < 32; ++i) {
            int io = i * 32 + o;
            float p1r = wr[io * TOT + p],      p1i = wi[io * TOT + p];
            float p2r = wr[io * TOT + 16 + q], p2i = wi[io * TOT + 16 + q];
            float a1r[4], a1i[4], a2r[4], a2i[4];
            a1r[0] = 1.f; a1i[0] = 0.f;
            a2r[0] = 1.f; a2i[0] = 0.f;
#pragma unroll
            for (int n = 1; n < 4; ++n) {
                a1r[n] = a1r[n-1] * p1r - a1i[n-1] * p1i;
                a1i[n] = a1r[n-1] * p1i + a1i[n-1] * p1r;
                a2r[n] = a2r[n-1] * p2r - a2i[n-1] * p2i;
                a2i[n] = a2r[n-1] * p2i + a2i[n-1] * p2r;
            }
#pragma unroll
            for (int n = 0; n < 4; ++n)
#pragma unroll
                for (int m = 0; m < 4; ++m) {
                    Sr[n][m] += a1r[n] * a2r[m] - a1i[n] * a2i[m];
                    Si[n][m] += a1r[n] * a2i[m] + a1i[n] * a2r[m];
                }
        }
        const float facs[4] = {1.f, 1.f, 0.5f, 0.16666666666f};
        const float isz = 1.0f / 16384.0f;
#pragma unroll
        for (int n = 0; n < 4; ++n)
#pragma unroll
            for (int m = 0; m < 4; ++m) {
                float fac = facs[n] * facs[m] * isz;
                Sv[(size_t)(o * 16 + n * 4 + m) * 256 + t] =
                    make_float2(Sr[n][m] * fac, Si[n][m] * fac);
            }
    } else if (bid < 416) {
        // ----- D_jk[i,o] = sum_pq phi_j[p] * R[p,q] * psi_k[q] (res moments) -----
        int base = (bid - 288) * 8;
        int wp = t >> 6, l = t & 63;
#pragma unroll
        for (int s = 0; s < 2; ++s) {
            int io = base + wp * 2 + s;
            float2 Dacc[9];
#pragma unroll
            for (int jk = 0; jk < 9; ++jk) Dacc[jk] = make_float2(0.f, 0.f);
#pragma unroll
            for (int k = 0; k < 4; ++k) {
                int e = l + 64 * k;
                int p = e >> 4, q = e & 15;
                float2 p1 = make_float2(wr[io * TOT + p], wi[io * TOT + p]);
                float i1 = 1.0f / (p1.x * p1.x + p1.y * p1.y);
                float2 phip = make_float2(-p1.x * i1, p1.y * i1);
                float2 p2 = make_float2(wr[io * TOT + 16 + q], wi[io * TOT + 16 + q]);
                float i2 = 1.0f / (p2.x * p2.x + p2.y * p2.y);
                float2 psip = make_float2(-p2.x * i2, p2.y * i2);
                float2 R = make_float2(wr[io * TOT + 32 + e], wi[io * TOT + 32 + e]);
                float2 Rphi[3] = {cmul(R, phip), R, cmul(R, p1)};
                float2 psi[3] = {psip, make_float2(1.f, 0.f), p2};
#pragma unroll
                for (int j = 0; j < 3; ++j)
#pragma unroll
                    for (int k2 = 0; k2 < 3; ++k2)
                        Dacc[j * 3 + k2] = cfma(Rphi[j], psi[k2], Dacc[j * 3 + k2]);
            }
#pragma unroll
            for (int jk = 0; jk < 9; ++jk) {
#pragma unroll
                for (int m = 32; m >= 1; m >>= 1) {
                    Dacc[jk].x += __shfl_xor(Dacc[jk].x, m);
                    Dacc[jk].y += __shfl_xor(Dacc[jk].y, m);
                }
            }
            if (l == 0) {
                int o = io & 31, i = io >> 5;
#pragma unroll
                for (int jk = 0; jk < 9; ++jk)
                    Dv[(size_t)(o * 32 + i) * 9 + jk] = Dacc[jk];
            }
        }
    } else {
        // ----- tf: Fourier bf16 tables -----
        for (int cidx = t; cidx < 1024; cidx += 256) {
            int tbl = cidx >> 9, mc = cidx & 511;
            int z = mc >> 2, cp = mc & 3;
            int c = cp ^ ((z >> 1) & 3);
            u16x8 v;
#pragma unroll
            for (int j = 0; j < 8; ++j) {
                int k = c * 8 + j, f = k & 15, part = k >> 4;
                float th = 0.049087385212340517f * (float)((f * z) & 127);
                float s, cs;
                sincosf(th, &s, &cs);
                float val = part ? ((tbl == 0) ? s : -s) : cs;
                v[j] = f2bf(val);
            }
            u16* dst = (tbl == 0 ? fA : fB) + mc * 8;
            *(u16x8*)dst = v;
        }
    }
}

// ============ k_mid: or1 (0..255) | or2p (256..2303), barrier-light bilinear forms
__global__ __launch_bounds__(256) void k_mid(const float* __restrict__ wr,
                                             const float* __restrict__ wi,
                                             const float2* __restrict__ alpha,
                                             const float2* __restrict__ Dv,
                                             float2* __restrict__ or1,
                                             float2* __restrict__ or2p) {
    __shared__ float2 CaL[4][9];
    const int bid = blockIdx.x;
    const int t = threadIdx.x;

    if (bid < 256) {
        // ----- or1[b,o,f,g] = sum_i alpha[b,i,f,g] * s1_i(f,g),
        //       s1_i = sum_jk D_jk[i,o] * chi_j[f] * xi_k[g] -----
        int bo = bid;
        int b = bo >> 5, o = bo & 31;
        int f = t >> 4, g = t & 15;
        float2 X[3], Xi[3];
        chi_basis(f, X);
        chi_basis(g, Xi);
        float2 B[9];
#pragma unroll
        for (int j = 0; j < 3; ++j)
#pragma unroll
            for (int k = 0; k < 3; ++k)
                B[j * 3 + k] = cmul(X[j], Xi[k]);
        float2 acc = make_float2(0.f, 0.f);
        for (int i = 0; i < 32; ++i) {
            const float2* Dp = Dv + (size_t)(o * 32 + i) * 9;
            float2 s1v = make_float2(0.f, 0.f);
#pragma unroll
            for (int jk = 0; jk < 9; ++jk)
                s1v = cfma(Dp[jk], B[jk], s1v);
            float2 a = alpha[(b * 32 + i) * 256 + t];
            acc = cfma(a, s1v, acc);
        }
        or1[bo * 256 + t] = acc;
    } else {
        // ----- or2 partial: T[p,q] = sum_jk Ca_jk[b,i] phi_j[p] psi_k[q]; acc += R*T -----
        int idx = bid - 256;
        int bo = idx & 255;
        int ic = idx >> 8;
        int b = bo >> 5, o = bo & 31;
        int wp = t >> 6, l = t & 63;
        // prologue: wave wp computes Ca for i = ic*4+wp
        {
            int i = ic * 4 + wp;
            float2 Ca[9];
#pragma unroll
            for (int jk = 0; jk < 9; ++jk) Ca[jk] = make_float2(0.f, 0.f);
#pragma unroll
            for (int k = 0; k < 4; ++k) {
                int e = l + 64 * k;
                int f = e >> 4, g = e & 15;
                float2 X[3], Xi[3];
                chi_basis(f, X);
                chi_basis(g, Xi);
                float2 a = alpha[(b * 32 + i) * 256 + e];
                float2 aX[3] = {cmul(a, X[0]), cmul(a, X[1]), cmul(a, X[2])};
#pragma unroll
                for (int j = 0; j < 3; ++j)
#pragma unroll
                    for (int k2 = 0; k2 < 3; ++k2)
                        Ca[j * 3 + k2] = cfma(aX[j], Xi[k2], Ca[j * 3 + k2]);
            }
#pragma unroll
            for (int jk = 0; jk < 9; ++jk) {
#pragma unroll
                for (int m = 32; m >= 1; m >>= 1) {
                    Ca[jk].x += __shfl_xor(Ca[jk].x, m);
                    Ca[jk].y += __shfl_xor(Ca[jk].y, m);
                }
            }
            if (l == 0) {
#pragma unroll
                for (int jk = 0; jk < 9; ++jk) CaL[wp][jk] = Ca[jk];
            }
        }
        __syncthreads();

        int p_ = t >> 4, q_ = t & 15;
        float2 acc = make_float2(0.f, 0.f);
#pragma unroll
        for (int ii = 0; ii < 4; ++ii) {
            int i = ic * 4 + ii;
            int io = i * 32 + o;
            float2 p1 = make_float2(wr[io * TOT + p_], wi[io * TOT + p_]);
            float i1 = 1.0f / (p1.x * p1.x + p1.y * p1.y);
            float2 phip = make_float2(-p1.x * i1, p1.y * i1);
            float2 p2 = make_float2(wr[io * TOT + 16 + q_], wi[io * TOT + 16 + q_]);
            float i2 = 1.0f / (p2.x * p2.x + p2.y * p2.y);
            float2 psip = make_float2(-p2.x * i2, p2.y * i2);
            float2 R = make_float2(wr[io * TOT + 32 + t], wi[io * TOT + 32 + t]);
            float2 c0 = CaL[ii][0], c1 = CaL[ii][1], c2 = CaL[ii][2];
            float2 c3 = CaL[ii][3], c4 = CaL[ii][4], c5 = CaL[ii][5];
            float2 c6 = CaL[ii][6], c7 = CaL[ii][7], c8 = CaL[ii][8];
            // col_k = Ca[0k]*phip + Ca[1k] + Ca[2k]*p1
            float2 col0 = cfma(c6, p1, cfma(c0, phip, c3));
            float2 col1 = cfma(c7, p1, cfma(c1, phip, c4));
            float2 col2 = cfma(c8, p1, cfma(c2, phip, c5));
            // T = col0*psip + col1 + col2*p2
            float2 T = cfma(col2, p2, cfma(col0, psip, col1));
            acc = cfma(R, T, acc);
        }
        or2p[(size_t)ic * 65536 + bo * 256 + t] = acc;
    }
}

// ============ k_x12m: single Fourier MFMA term + 4x4 Taylor polynomial for x2.
__global__ __launch_bounds__(512, 4) void k_x12m(
        const float2* __restrict__ or1v,
        const float2* __restrict__ or2p,
        const float2* __restrict__ Sv,
        const u16* __restrict__ fA,
        const u16* __restrict__ fB,
        float* __restrict__ out) {
    __shared__ u16 EA[2048];
    __shared__ u16 EB[4096];
    __shared__ u16 GL[2048];
    __shared__ float2 SM1[256];
    __shared__ float2 SM2[256];
    __shared__ float CP[16];

    const int t = threadIdx.x;
    const int l = t & 63, w = t >> 6;
    const int bid = blockIdx.x;
    const int o = bid & 31, b = (bid >> 5) & 7, zh = bid >> 8;
    const int bo = b * 32 + o;
    const int q = l & 15, c4 = l >> 4, k0 = c4 * 8;

    for (int ch = w; ch < 12; ch += 8) {
        const u16* g;
        u16* d;
        if (ch < 4) { g = fA + zh * 2048 + ch * 512 + l * 8; d = &EA[ch * 512]; }
        else { g = fB + (ch - 4) * 512 + l * 8; d = &EB[(ch - 4) * 512]; }
        __builtin_amdgcn_global_load_lds(
            (const __attribute__((address_space(1))) unsigned*)g,
            (__attribute__((address_space(3))) unsigned*)d, 16, 0, 0);
    }

    if (t < 256) {
        float sr = 0.f, si = 0.f;
#pragma unroll
        for (int ic = 0; ic < 8; ++ic) {
            float2 v = or2p[(size_t)ic * 65536 + bo * 256 + t];
            sr += v.x; si += v.y;
        }
        SM2[t] = make_float2(sr, si);
        SM1[t] = or1v[bo * 256 + t];
    }
    __syncthreads();

    {
        int gidx = t >> 5;
        int j = t & 31;
        const float2* Sg = Sv + (size_t)(o * 16 + gidx) * 256;
        float part = 0.f;
#pragma unroll
        for (int k = 0; k < 8; ++k) {
            int pq = j + 32 * k;
            float2 s = Sg[pq];
            float2 v = SM2[pq];
            part += v.x * s.x - v.y * s.y;
        }
#pragma unroll
        for (int msk = 16; msk >= 1; msk >>= 1)
            part += __shfl_xor(part, msk, 32);
        if (j == 0) CP[gidx] = part;
    }

    short8 mF0, mF1;
#pragma unroll
    for (int j = 0; j < 8; ++j) {
        int k = k0 + j, f = k & 15;
        float2 m1 = SM1[f * 16 + q];
        if (k < 16) { mF0[j] = (short)f2bf(m1.x); mF1[j] = (short)f2bf(m1.y); }
        else        { mF0[j] = (short)f2bf(-m1.y); mF1[j] = (short)f2bf(m1.x); }
    }
    const short8 bF = (w & 1) ? mF1 : mF0;

    const int zt_g = w >> 1;
    const int zL_g = zt_g * 16 + q;
    const int cw_g = c4 ^ ((zL_g >> 1) & 3);
    const int kk_g = q + ((w & 1) << 4);
    const int x_ = w * 16 + q;
    const int cb_ = c4 ^ ((x_ >> 1) & 3);

    {
        short8 aG = *(const short8*)&EA[zL_g * 32 + cw_g * 8];
        f32x4 g = (f32x4){0.f, 0.f, 0.f, 0.f};
        g = __builtin_amdgcn_mfma_f32_16x16x32_bf16(aG, bF, g, 0, 0, 0);
#pragma unroll
        for (int r = 0; r < 4; ++r) {
            int zz = zt_g * 16 + c4 * 4 + r;
            int cc = (kk_g >> 3) ^ ((zz >> 1) & 3);
            GL[zz * 32 + cc * 8 + (kk_g & 7)] = f2bf(g[r]);
        }
    }
    __syncthreads();

    f32x4 acc[4];
    {
        short8 bf = *(const short8*)&EB[x_ * 32 + cb_ * 8];
#pragma unroll
        for (int zt = 0; zt < 4; ++zt) {
            int zL = zt * 16 + q;
            int ca = c4 ^ ((zL >> 1) & 3);
            short8 af = *(const short8*)&GL[zL * 32 + ca * 8];
            f32x4 a = (f32x4){0.f, 0.f, 0.f, 0.f};
            acc[zt] = __builtin_amdgcn_mfma_f32_16x16x32_bf16(af, bf, a, 0, 0, 0);
        }
    }

    const float sc = 1.0f / 16384.0f;
    const float tx = (float)x_ * 0.007874015748031496f;
    float R[4];
#pragma unroll
    for (int n = 0; n < 4; ++n)
        R[n] = ((CP[n * 4 + 3] * tx + CP[n * 4 + 2]) * tx + CP[n * 4 + 1]) * tx + CP[n * 4 + 0];
#pragma unroll
    for (int zt = 0; zt < 4; ++zt) {
        int zbase = zh * 64 + zt * 16 + c4 * 4;
        f32x4 a = acc[zt];
#pragma unroll
        for (int r = 0; r < 4; ++r) {
            float tz = (float)(zbase + r) * 0.007874015748031496f;
            float poly = ((R[3] * tz + R[2]) * tz + R[1]) * tz + R[0];
            out[(size_t)bo * 16384 + (zbase + r) * 128 + x_] = a[r] * sc + poly;
        }
    }
}

extern "C" void kernel_launch(void* const* d_in, const int* in_sizes, int n_in,
                              void* d_out, int out_size, void* d_ws, size_t ws_size,
                              hipStream_t stream) {
    const float* x  = (const float*)d_in[0];
    const float* wr = (const float*)d_in[1];
    const float* wi = (const float*)d_in[2];
    float* out = (float*)d_out;
    float* ws = (float*)d_ws;

    float2* alpha = (float2*)(ws + 256);
    float2* Dv    = (float2*)(ws + 1179904);
    float2* or1   = (float2*)(ws + 1704192);
    float2* Sv    = (float2*)(ws + 1966336);
    u16*    fA    = (u16*)(ws + 6160640);
    u16*    fB    = (u16*)(ws + 6162688);
    float2* or2p  = (float2*)(ws + 6164736);

    hipLaunchKernelGGL(k_pre,  dim3(417),  dim3(256), 0, stream,
                       x, wr, wi, Sv, Dv, fA, fB, alpha);
    hipLaunchKernelGGL(k_mid,  dim3(2304), dim3(256), 0, stream,
                       wr, wi, alpha, Dv, or1, or2p);
    hipLaunchKernelGGL(k_x12m, dim3(512),  dim3(512), 0, stream,
                       or1, or2p, Sv, fA, fB, out);
}